// Round 9
// baseline (28.027 us; speedup 1.0000x reference)
//
#include <hip/hip_runtime.h>

// ParticleI2cCell: pairwise Gaussian loglik (P x P, D=4) + two row-LSEs.
// smoothed[i] = log(sum_j e_ij*exp(w_j)) - log(sum_j e_ij*exp(lw_j))
// e_ij = exp(m_i . s_j - ||s_j||^2/2)   [exp(-||m_i||^2/2) cancels in the
// log-ratio and is dropped].
//
// R8 landed the right structure (fused, no partials, no second kernel):
// 27 us. Residual gap vs the ~6 us VALU floor is latency: 16 waves/CU and
// loads not in flight across unrolled bodies. R9: BLOCK=512 -> 32 waves/CU
// (100% occupancy, launch_bounds(512,8) pins VGPR<=64), plus an explicit
// distance-2 register pipeline (even/odd slots, no dynamic indexing).

constexpr float LOG2E = 1.4426950408889634f;
constexpr float LN2   = 0.6931471805599453f;

// ---------------- precompute: j-table [P][8] AoS + means SoA [4][P] --------
__global__ __launch_bounds__(256) void precompute_k(
    const float* __restrict__ particles,
    const float* __restrict__ samples,
    const float* __restrict__ weights,
    const float* __restrict__ log_weights,
    const float* __restrict__ A,
    const float* __restrict__ B,
    const float* __restrict__ log_sigma,
    float* __restrict__ jdata,   // [P][8]: {LOG2E*s0..s3, K*||s||^2, e^lw, e^w, 0}
    float* __restrict__ msoa,    // [4][P] scaled means
    int P)
{
    int i = blockIdx.x * blockDim.x + threadIdx.x;
    if (i >= P) return;

    const float K = -0.5f * LOG2E;

    float inv_s[4];
#pragma unroll
    for (int k = 0; k < 4; ++k)
        inv_s[k] = __builtin_amdgcn_exp2f(-log_sigma[k] * LOG2E);

    float4 sv = reinterpret_cast<const float4*>(samples)[i];
    float s0 = sv.x * inv_s[0], s1 = sv.y * inv_s[1];
    float s2 = sv.z * inv_s[2], s3 = sv.w * inv_s[3];
    float sn = s0*s0 + s1*s1 + s2*s2 + s3*s3;

    float4* jd = reinterpret_cast<float4*>(jdata + (size_t)i * 8);
    jd[0] = make_float4(LOG2E*s0, LOG2E*s1, LOG2E*s2, LOG2E*s3);
    jd[1] = make_float4(K * sn,
                        __builtin_amdgcn_exp2f(log_weights[i] * LOG2E),
                        __builtin_amdgcn_exp2f(weights[i] * LOG2E),
                        0.f);

    const float2* p2 = reinterpret_cast<const float2*>(particles) + (size_t)i * 3;
    float2 x01 = p2[0], x23 = p2[1], u01 = p2[2];
    float x[4] = {x01.x, x01.y, x23.x, x23.y};
    float u[2] = {u01.x, u01.y};
#pragma unroll
    for (int k = 0; k < 4; ++k) {
        float mean =       A[k*4+0] * x[0];
        mean = fmaf(A[k*4+1], x[1], mean);
        mean = fmaf(A[k*4+2], x[2], mean);
        mean = fmaf(A[k*4+3], x[3], mean);
        mean = fmaf(B[k*2+0], u[0], mean);
        mean = fmaf(B[k*2+1], u[1], mean);
        msoa[(size_t)k * P + i] = mean * inv_s[k];
    }
}

// ---------------- fused pair + in-block reduce -----------------------------
// grid = P/TR = 1024 blocks of BLOCK=512 -> 4 blocks/CU, 32 waves/CU.
// Thread t sweeps j = t + BLOCK*it (iters = P/BLOCK = 16), distance-2
// register pipeline. Row means are block-uniform -> SGPRs (1 SGPR operand
// per FMA is legal).
template <int TR, int BLOCK>
__global__ __launch_bounds__(BLOCK, 8) void pair_fused(
    const float* __restrict__ jdata,   // [P][8]
    const float* __restrict__ msoa,    // [4][P]
    float* __restrict__ out, int P)
{
    constexpr int NW = BLOCK / 64;

    const int tid  = threadIdx.x;
    const int lane = tid & 63;
    const int wv   = tid >> 6;
    const int rowBase = blockIdx.x * TR;

    // block-uniform row means -> scalar loads / SGPRs
    float m0[TR], m1[TR], m2[TR], m3[TR], a1[TR], a2[TR];
#pragma unroll
    for (int r = 0; r < TR; ++r) {
        m0[r] = msoa[0 * (size_t)P + rowBase + r];
        m1[r] = msoa[1 * (size_t)P + rowBase + r];
        m2[r] = msoa[2 * (size_t)P + rowBase + r];
        m3[r] = msoa[3 * (size_t)P + rowBase + r];
        a1[r] = 0.f;
        a2[r] = 0.f;
    }

    const float4* jf = reinterpret_cast<const float4*>(jdata);
    const int iters = P / BLOCK;               // 16 at P=8192 (even)

#define COMPUTE(AV, BV)                                        \
    {                                                          \
        _Pragma("unroll")                                      \
        for (int r = 0; r < TR; ++r) {                         \
            float t = fmaf(m0[r], (AV).x, (BV).x);             \
            t = fmaf(m1[r], (AV).y, t);                        \
            t = fmaf(m2[r], (AV).z, t);                        \
            t = fmaf(m3[r], (AV).w, t);                        \
            float e = __builtin_amdgcn_exp2f(t);               \
            a1[r] = fmaf(e, (BV).y, a1[r]);                    \
            a2[r] = fmaf(e, (BV).z, a2[r]);                    \
        }                                                      \
    }

    // distance-2 software pipeline (even/odd slots, no dynamic indexing)
    float4 avA = jf[2 * (size_t)tid];
    float4 bvA = jf[2 * (size_t)tid + 1];
    float4 avB = jf[2 * ((size_t)tid + BLOCK)];
    float4 bvB = jf[2 * ((size_t)tid + BLOCK) + 1];

    int it = 0;
#pragma unroll 1
    for (; it + 2 < iters; it += 2) {
        const size_t jC = (size_t)(it + 2) * BLOCK + tid;
        float4 avC = jf[2 * jC];
        float4 bvC = jf[2 * jC + 1];
        COMPUTE(avA, bvA);
        const size_t jD = (size_t)(it + 3) * BLOCK + tid;
        float4 avD = jf[2 * jD];
        float4 bvD = jf[2 * jD + 1];
        COMPUTE(avB, bvB);
        avA = avC; bvA = bvC;
        avB = avD; bvB = bvD;
    }
    COMPUTE(avA, bvA);
    COMPUTE(avB, bvB);
#undef COMPUTE

    // ---- 64-lane butterfly per row (fixed order -> deterministic) ----
#pragma unroll
    for (int r = 0; r < TR; ++r) {
#pragma unroll
        for (int mask = 32; mask >= 1; mask >>= 1) {
            a1[r] += __shfl_xor(a1[r], mask, 64);
            a2[r] += __shfl_xor(a2[r], mask, 64);
        }
    }

    // ---- cross-wave combine via small LDS, fixed order ----
    __shared__ float red[NW][2 * TR];
    if (lane == 0) {
#pragma unroll
        for (int r = 0; r < TR; ++r) {
            red[wv][r]      = a1[r];
            red[wv][TR + r] = a2[r];
        }
    }
    __syncthreads();
    if (tid < TR) {
        float s1 = 0.f, s2 = 0.f;
#pragma unroll
        for (int w = 0; w < NW; ++w) {
            s1 += red[w][tid];
            s2 += red[w][TR + tid];
        }
        out[rowBase + tid] =
            (__builtin_amdgcn_logf(s2) - __builtin_amdgcn_logf(s1)) * LN2;
    }
}

extern "C" void kernel_launch(void* const* d_in, const int* in_sizes, int n_in,
                              void* d_out, int out_size, void* d_ws, size_t ws_size,
                              hipStream_t stream)
{
    const float* particles   = (const float*)d_in[0];
    const float* samples     = (const float*)d_in[1];
    const float* weights     = (const float*)d_in[2];
    const float* log_weights = (const float*)d_in[3];
    const float* A           = (const float*)d_in[4];
    const float* B           = (const float*)d_in[5];
    const float* log_sigma   = (const float*)d_in[6];

    const int P = in_sizes[2];  // weights is (P,)

    // ws layout: jdata P*8 | msoa 4*P   (393 KB at P=8192)
    float* jdata = (float*)d_ws;
    float* msoa  = jdata + (size_t)P * 8;

    constexpr int BLOCK = 512, TR = 8;

    precompute_k<<<(P + 255) / 256, 256, 0, stream>>>(
        particles, samples, weights, log_weights, A, B, log_sigma,
        jdata, msoa, P);

    pair_fused<TR, BLOCK><<<P / TR, BLOCK, 0, stream>>>(
        jdata, msoa, (float*)d_out, P);
}

// Round 10
// 27.872 us; speedup vs baseline: 1.0056x; 1.0056x over previous
//
#include <hip/hip_runtime.h>

// ParticleI2cCell: pairwise Gaussian loglik (P x P, D=4) + two row-LSEs.
// smoothed[i] = log(sum_j e_ij*exp(w_j)) - log(sum_j e_ij*exp(lw_j))
// e_ij = exp(m_i . s_j - ||s_j||^2/2)   [exp(-||m_i||^2/2) cancels in the
// log-ratio and is dropped].
//
// R9 lesson: 32 waves/CU == 16 waves/CU at fixed TR=8 -> not latency-bound.
// Model: issue floor ~9us (22 cyc per wave-pair-row incl. 8-cyc exp) with a
// VMEM-path co-limiter (each block streams the full 256KB j-table; TR=8 =>
// 268MB through L1-miss path, ~73% TA/L1 utilization). R10: TR=16 halves
// per-cycle VMEM demand and total L2 traffic at constant issue work.
// launch_bounds(512,4) avoids the VGPR-64 spill risk R9 ran under.

constexpr float LOG2E = 1.4426950408889634f;
constexpr float LN2   = 0.6931471805599453f;

// ---------------- precompute: j-table [P][8] AoS + means SoA [4][P] --------
__global__ __launch_bounds__(256) void precompute_k(
    const float* __restrict__ particles,
    const float* __restrict__ samples,
    const float* __restrict__ weights,
    const float* __restrict__ log_weights,
    const float* __restrict__ A,
    const float* __restrict__ B,
    const float* __restrict__ log_sigma,
    float* __restrict__ jdata,   // [P][8]: {LOG2E*s0..s3, K*||s||^2, e^lw, e^w, 0}
    float* __restrict__ msoa,    // [4][P] scaled means
    int P)
{
    int i = blockIdx.x * blockDim.x + threadIdx.x;
    if (i >= P) return;

    const float K = -0.5f * LOG2E;

    float inv_s[4];
#pragma unroll
    for (int k = 0; k < 4; ++k)
        inv_s[k] = __builtin_amdgcn_exp2f(-log_sigma[k] * LOG2E);

    float4 sv = reinterpret_cast<const float4*>(samples)[i];
    float s0 = sv.x * inv_s[0], s1 = sv.y * inv_s[1];
    float s2 = sv.z * inv_s[2], s3 = sv.w * inv_s[3];
    float sn = s0*s0 + s1*s1 + s2*s2 + s3*s3;

    float4* jd = reinterpret_cast<float4*>(jdata + (size_t)i * 8);
    jd[0] = make_float4(LOG2E*s0, LOG2E*s1, LOG2E*s2, LOG2E*s3);
    jd[1] = make_float4(K * sn,
                        __builtin_amdgcn_exp2f(log_weights[i] * LOG2E),
                        __builtin_amdgcn_exp2f(weights[i] * LOG2E),
                        0.f);

    const float2* p2 = reinterpret_cast<const float2*>(particles) + (size_t)i * 3;
    float2 x01 = p2[0], x23 = p2[1], u01 = p2[2];
    float x[4] = {x01.x, x01.y, x23.x, x23.y};
    float u[2] = {u01.x, u01.y};
#pragma unroll
    for (int k = 0; k < 4; ++k) {
        float mean =       A[k*4+0] * x[0];
        mean = fmaf(A[k*4+1], x[1], mean);
        mean = fmaf(A[k*4+2], x[2], mean);
        mean = fmaf(A[k*4+3], x[3], mean);
        mean = fmaf(B[k*2+0], u[0], mean);
        mean = fmaf(B[k*2+1], u[1], mean);
        msoa[(size_t)k * P + i] = mean * inv_s[k];
    }
}

// ---------------- fused pair + in-block reduce -----------------------------
// grid = P/TR = 512 blocks of BLOCK=512 -> 2 blocks/CU, 16 waves/CU.
// Thread t sweeps j = t + BLOCK*it (iters = P/BLOCK = 16), distance-2
// register pipeline. TR=16 rows/block: means are block-uniform (SGPRs).
template <int TR, int BLOCK>
__global__ __launch_bounds__(BLOCK, 4) void pair_fused(
    const float* __restrict__ jdata,   // [P][8]
    const float* __restrict__ msoa,    // [4][P]
    float* __restrict__ out, int P)
{
    constexpr int NW = BLOCK / 64;

    const int tid  = threadIdx.x;
    const int lane = tid & 63;
    const int wv   = tid >> 6;
    const int rowBase = blockIdx.x * TR;

    // block-uniform row means -> scalar loads / SGPRs
    float m0[TR], m1[TR], m2[TR], m3[TR], a1[TR], a2[TR];
#pragma unroll
    for (int r = 0; r < TR; ++r) {
        m0[r] = msoa[0 * (size_t)P + rowBase + r];
        m1[r] = msoa[1 * (size_t)P + rowBase + r];
        m2[r] = msoa[2 * (size_t)P + rowBase + r];
        m3[r] = msoa[3 * (size_t)P + rowBase + r];
        a1[r] = 0.f;
        a2[r] = 0.f;
    }

    const float4* jf = reinterpret_cast<const float4*>(jdata);
    const int iters = P / BLOCK;               // 16 at P=8192 (even)

#define COMPUTE(AV, BV)                                        \
    {                                                          \
        _Pragma("unroll")                                      \
        for (int r = 0; r < TR; ++r) {                         \
            float t = fmaf(m0[r], (AV).x, (BV).x);             \
            t = fmaf(m1[r], (AV).y, t);                        \
            t = fmaf(m2[r], (AV).z, t);                        \
            t = fmaf(m3[r], (AV).w, t);                        \
            float e = __builtin_amdgcn_exp2f(t);               \
            a1[r] = fmaf(e, (BV).y, a1[r]);                    \
            a2[r] = fmaf(e, (BV).z, a2[r]);                    \
        }                                                      \
    }

    // distance-2 software pipeline (even/odd slots, no dynamic indexing)
    float4 avA = jf[2 * (size_t)tid];
    float4 bvA = jf[2 * (size_t)tid + 1];
    float4 avB = jf[2 * ((size_t)tid + BLOCK)];
    float4 bvB = jf[2 * ((size_t)tid + BLOCK) + 1];

    int it = 0;
#pragma unroll 1
    for (; it + 2 < iters; it += 2) {
        const size_t jC = (size_t)(it + 2) * BLOCK + tid;
        float4 avC = jf[2 * jC];
        float4 bvC = jf[2 * jC + 1];
        COMPUTE(avA, bvA);
        const size_t jD = (size_t)(it + 3) * BLOCK + tid;
        float4 avD = jf[2 * jD];
        float4 bvD = jf[2 * jD + 1];
        COMPUTE(avB, bvB);
        avA = avC; bvA = bvC;
        avB = avD; bvB = bvD;
    }
    COMPUTE(avA, bvA);
    COMPUTE(avB, bvB);
#undef COMPUTE

    // ---- 64-lane butterfly per row (fixed order -> deterministic) ----
#pragma unroll
    for (int r = 0; r < TR; ++r) {
#pragma unroll
        for (int mask = 32; mask >= 1; mask >>= 1) {
            a1[r] += __shfl_xor(a1[r], mask, 64);
            a2[r] += __shfl_xor(a2[r], mask, 64);
        }
    }

    // ---- cross-wave combine via small LDS, fixed order ----
    __shared__ float red[NW][2 * TR];
    if (lane == 0) {
#pragma unroll
        for (int r = 0; r < TR; ++r) {
            red[wv][r]      = a1[r];
            red[wv][TR + r] = a2[r];
        }
    }
    __syncthreads();
    if (tid < TR) {
        float s1 = 0.f, s2 = 0.f;
#pragma unroll
        for (int w = 0; w < NW; ++w) {
            s1 += red[w][tid];
            s2 += red[w][TR + tid];
        }
        out[rowBase + tid] =
            (__builtin_amdgcn_logf(s2) - __builtin_amdgcn_logf(s1)) * LN2;
    }
}

extern "C" void kernel_launch(void* const* d_in, const int* in_sizes, int n_in,
                              void* d_out, int out_size, void* d_ws, size_t ws_size,
                              hipStream_t stream)
{
    const float* particles   = (const float*)d_in[0];
    const float* samples     = (const float*)d_in[1];
    const float* weights     = (const float*)d_in[2];
    const float* log_weights = (const float*)d_in[3];
    const float* A           = (const float*)d_in[4];
    const float* B           = (const float*)d_in[5];
    const float* log_sigma   = (const float*)d_in[6];

    const int P = in_sizes[2];  // weights is (P,)

    // ws layout: jdata P*8 | msoa 4*P   (393 KB at P=8192)
    float* jdata = (float*)d_ws;
    float* msoa  = jdata + (size_t)P * 8;

    constexpr int BLOCK = 512, TR = 16;

    precompute_k<<<(P + 255) / 256, 256, 0, stream>>>(
        particles, samples, weights, log_weights, A, B, log_sigma,
        jdata, msoa, P);

    pair_fused<TR, BLOCK><<<P / TR, BLOCK, 0, stream>>>(
        jdata, msoa, (float*)d_out, P);
}